// Round 3
// baseline (965.302 us; speedup 1.0000x reference)
//
#include <hip/hip_runtime.h>

// Stacked LSTM B=2048,T=512,IN=4,H=64,L=4,OUT=5 — WAVE-PER-LAYER, in-register
// recurrence. R11/R12 post-mortem: all 4-waves-per-layer structures (flag ring
// 603us, barrier skew 639us, half-phase 713us) wall at ~2.4x the matrix-pipe
// floor (64 MFMA/SIMD/step x 18.5 cyc = 1184 cyc = 255us) because the
// h(t)->h(t+1) recurrence crosses waves/SIMDs through LDS+sync EVERY step,
// and lockstep phases serialize MFMA vs pointwise (barrier cost ~343 cyc
// measured via R11->R12 delta).
// Here: block = 256 threads = 4 waves; wave l owns layer l ENTIRELY
// (8 batches, 64 units, 256 gates): 64 MFMA/wave/step (48 for l=0), weights
// as 256 VGPRs of B-frags (1 wave/SIMD -> 512-VGPR budget). The recurrence
// is wave-local: h(t) -> own LDS slot (same-wave in-order write->read, no
// sync, and each step's release-flag store drains lgkmcnt anyway) -> A-frag
// of step t+1. Cross-layer edge (only) uses flags + depth-4 slot ring with
// back-pressure: fwd poll flgw[l-1]>=t+1 before input frags; publish
// flgr[l]=t+1 after consuming; writer polls flgr[l+1]>=t-3 before
// overwriting slot t&3. Steady state: polls pass, no barriers in loop.
// Single wave dual-issues: MFMA(nt) on matrix pipe overlaps pointwise(nt-1)
// on trans pipe -> step -> max(1184 matrix, ~940 VALU) + bubbles.
// Math identical to validated R10 (absmax 4.9e-4): f16 weights+acts,
// prescale -log2e (i,f,o) / +2log2e (g) -> direct exp2; zero-C MFMA, bias in
// pointwise. k-permutation = IDENTITY now (unit u at k=u). LDS h rows 128 B,
// XOR-swizzle byte^=((r&7)<<4) on both write and read (T2 both-sides rule).
// A-frag: lane: row=lane&15, k=(lane>>4)*8+e. C: col=lane&15 (unit),
// row=(lane>>4)*4+reg (batch, real rows r=4q+rr, rr<2, b=2q+rr).

#define B_    2048
#define T_    512
#define H_    64
#define OUT_  5
#define LOG2E 1.44269504088896340736f

typedef _Float16 f16;
typedef __attribute__((ext_vector_type(4))) _Float16 f16x4;
typedef __attribute__((ext_vector_type(8))) _Float16 f16x8;
typedef __attribute__((ext_vector_type(4))) float f32x4;
typedef __attribute__((ext_vector_type(2))) unsigned long long u64x2;

__device__ __forceinline__ float rcpf(float v) { return __builtin_amdgcn_rcpf(v); }
__device__ __forceinline__ float ex2(float v)  { return __builtin_amdgcn_exp2f(v); }

__global__ __launch_bounds__(256, 1) void lstm_wpl_k(
    const float* __restrict__ x,      // [B,T,4]
    const float* __restrict__ W_ih0,  // [256,4]
    const float* __restrict__ W_ihr,  // [3,256,64]
    const float* __restrict__ W_hh,   // [4,256,64]
    const float* __restrict__ b_ih,   // [4,256]
    const float* __restrict__ b_hh,   // [4,256]
    const float* __restrict__ W_fc,   // [5,64]
    const float* __restrict__ b_fc,   // [5]
    float* __restrict__ out)          // [B,5]
{
    const int tid  = threadIdx.x;
    const int l    = tid >> 6;        // wave = layer 0..3
    const int lane = tid & 63;
    const int q    = lane >> 4;
    const int u15  = lane & 15;
    const int b0   = blockIdx.x * 8;

    // h store: [layer][slot 0..3][16 rows x 64 f16], row = 128 B, swizzled. 32 KB.
    __shared__ f16  hbuf[4][4][1024];
    __shared__ f16  xlds[T_][8][4];    // 32 KB
    __shared__ float hf[8][H_ + 1];
    __shared__ int  flgw[4], flgr[4];

    for (int k = tid; k < 8192; k += 256) ((unsigned*)hbuf)[k] = 0u;
    if (tid < 4) { flgw[tid] = 0; flgr[tid] = 0; }

    // ---- one-time x preload -> xlds (f16) ----
#pragma unroll
    for (int k = 0; k < 16; ++k) {
        const int idx = tid + k * 256;               // 0..4095
        const int bb  = idx >> 9, tt = idx & 511;
        const float4 v = *(const float4*)(x + (size_t)(b0 + bb) * (T_ * 4) + tt * 4);
        f16x4 h4; h4[0] = (f16)v.x; h4[1] = (f16)v.y; h4[2] = (f16)v.z; h4[3] = (f16)v.w;
        *(f16x4*)&xlds[tt][bb][0] = h4;
    }

    // ---- weights -> B-frags: Wf[nt][g4][kt], 64 frags x f16x8 = 256 VGPR ----
    const float* Whh = W_hh + (size_t)l * 256 * 64;
    const float* Wih = (l == 0) ? W_ih0 : (W_ihr + (size_t)(l - 1) * 256 * 64);
    const float scg[4] = {-LOG2E, -LOG2E, 2.0f * LOG2E, -LOG2E};

    f16x8 Wf[4][4][4];
    float biasv[4][4];
#pragma unroll
    for (int nt = 0; nt < 4; ++nt)
#pragma unroll
    for (int g4 = 0; g4 < 4; ++g4) {
        const int n = g4 * 64 + nt * 16 + u15;
        biasv[nt][g4] = (b_ih[l * 256 + n] + b_hh[l * 256 + n]) * scg[g4];
#pragma unroll
        for (int kt = 0; kt < 4; ++kt) {
            f16x8 f;
#pragma unroll
            for (int e = 0; e < 8; ++e) {
                float wv;
                if (kt < 2)          wv = Whh[n * 64 + kt * 32 + q * 8 + e];
                else if (l == 0)     wv = (kt == 2 && q == 0 && e < 4) ? Wih[n * 4 + e] : 0.0f;
                else                 wv = Wih[n * 64 + (kt - 2) * 32 + q * 8 + e];
                f[e] = (f16)(wv * scg[g4]);
            }
            Wf[nt][g4][kt] = f;
        }
    }

    // ---- per-lane LDS offsets ----
    const int rA    = u15;                          // A-frag row
    const int swzA  = (rA & 7) << 4;
    const int roffA = (rA * 128 + q * 16) ^ swzA;   // k-octets 0..3   (kt0 / input kt2)
    const int roffB = (rA * 128 + 64 + q * 16) ^ swzA; // k-octets 4..7 (kt1 / input kt3)
    char* ownB      = (char*)&hbuf[l][0][0];
    const char* inB = (const char*)&hbuf[(l > 0) ? (l - 1) : 0][0][0];

    int woff[2][4];
#pragma unroll
    for (int rr = 0; rr < 2; ++rr) {
        const int r = 4 * q + rr;
#pragma unroll
        for (int nt = 0; nt < 4; ++nt)
            woff[rr][nt] = (r * 128 + nt * 32 + u15 * 2) ^ ((r & 7) << 4);
    }
    const int  xb  = 2 * (rA >> 2) + (rA & 3);      // batch for x-frag row
    const bool xok = (lane < 16) && ((rA & 3) < 2); // q==0, real rows only

    __syncthreads();                  // zero-init + xlds visible

    const f32x4 Z0 = {0.f, 0.f, 0.f, 0.f};
    float cst[8];
#pragma unroll
    for (int i = 0; i < 8; ++i) cst[i] = 0.f;

    auto waitge = [&](int* f, int tgt) {
        unsigned g = 0;
        for (;;) {
            const int v = __hip_atomic_load(f, __ATOMIC_ACQUIRE, __HIP_MEMORY_SCOPE_WORKGROUP);
            if (v >= tgt) break;
            if (++g > 16) __builtin_amdgcn_s_sleep(1);
            if (g > (1u << 18)) break;               // degrade: wrong answer, not hang
        }
    };

#pragma unroll 1
    for (int t = 0; t < T_; ++t) {
        if (l < 3) waitge(&flgr[l + 1], t - 3);      // ring WAR back-pressure
        if (l > 0) waitge(&flgw[l - 1], t + 1);      // input h_{l-1}(t) ready

        // ---- A fragments ----
        const char* ro = ownB + (size_t)(((t + 3) & 3) * 2048);   // h_l(t-1)
        const f16x8 A0 = *(const f16x8*)(ro + roffA);
        const f16x8 A1 = *(const f16x8*)(ro + roffB);
        f16x8 A2, A3;
        if (l > 0) {
            const char* ri = inB + (size_t)((t & 3) * 2048);      // h_{l-1}(t)
            A2 = *(const f16x8*)(ri + roffA);
            A3 = *(const f16x8*)(ri + roffB);
            if (lane == 0)   // release drains this wave's lgkm -> frags consumed
                __hip_atomic_store(&flgr[l], t + 1, __ATOMIC_RELEASE,
                                   __HIP_MEMORY_SCOPE_WORKGROUP);
        } else {
            unsigned long long xw = 0ull;
            if (xok) xw = *(const unsigned long long*)&xlds[t][xb][0];
            u64x2 tmp; tmp[0] = xw; tmp[1] = 0ull;
            A2 = __builtin_bit_cast(f16x8, tmp);     // x(t) at k=64..67, rest 0
            A3 = A2;                                  // unused for l==0
        }

        char* wr = ownB + (size_t)((t & 3) * 2048);

        // ---- per unit-tile: 16 (12) MFMA -> pointwise -> h writes ----
#pragma unroll
        for (int nt = 0; nt < 4; ++nt) {
            f32x4 acc[4];
#pragma unroll
            for (int g4 = 0; g4 < 4; ++g4)
                acc[g4] = __builtin_amdgcn_mfma_f32_16x16x32_f16(A0, Wf[nt][g4][0], Z0, 0, 0, 0);
#pragma unroll
            for (int g4 = 0; g4 < 4; ++g4)
                acc[g4] = __builtin_amdgcn_mfma_f32_16x16x32_f16(A1, Wf[nt][g4][1], acc[g4], 0, 0, 0);
#pragma unroll
            for (int g4 = 0; g4 < 4; ++g4)
                acc[g4] = __builtin_amdgcn_mfma_f32_16x16x32_f16(A2, Wf[nt][g4][2], acc[g4], 0, 0, 0);
            if (l > 0) {                              // kt3 identically 0 for l==0
#pragma unroll
                for (int g4 = 0; g4 < 4; ++g4)
                    acc[g4] = __builtin_amdgcn_mfma_f32_16x16x32_f16(A3, Wf[nt][g4][3], acc[g4], 0, 0, 0);
            }
#pragma unroll
            for (int rr = 0; rr < 2; ++rr) {
                const float si = rcpf(1.0f + ex2(acc[0][rr] + biasv[nt][0]));
                const float sf = rcpf(1.0f + ex2(acc[1][rr] + biasv[nt][1]));
                const float tg = 1.0f - 2.0f * rcpf(1.0f + ex2(acc[2][rr] + biasv[nt][2]));
                const float so = rcpf(1.0f + ex2(acc[3][rr] + biasv[nt][3]));
                const float c  = sf * cst[nt * 2 + rr] + si * tg;
                cst[nt * 2 + rr] = c;
                const float tc = 1.0f - 2.0f * rcpf(1.0f + ex2(c * (2.0f * LOG2E)));
                const float h  = so * tc;
                *(f16*)(wr + woff[rr][nt]) = (f16)h;  // h(t) -> slot t&3, k=u
                if (l == 3 && t == T_ - 1) hf[2 * q + rr][nt * 16 + u15] = h;
            }
        }

        if (l < 3 && lane == 0)       // release: h(t) writes drained & visible
            __hip_atomic_store(&flgw[l], t + 1, __ATOMIC_RELEASE,
                               __HIP_MEMORY_SCOPE_WORKGROUP);
    }

    // ---- FC on h(T-1) of layer 3 ----
    __syncthreads();
    if (tid < 8 * OUT_) {
        const int b = tid / OUT_, o = tid % OUT_;
        float a = b_fc[o];
#pragma unroll
        for (int k = 0; k < H_; ++k)
            a = fmaf(hf[b][k], W_fc[o * H_ + k], a);
        out[(b0 + b) * OUT_ + o] = a;
    }
}

extern "C" void kernel_launch(void* const* d_in, const int* in_sizes, int n_in,
                              void* d_out, int out_size, void* d_ws, size_t ws_size,
                              hipStream_t stream) {
    const float* x     = (const float*)d_in[0];
    const float* W_ih0 = (const float*)d_in[1];
    const float* W_ihr = (const float*)d_in[2];
    const float* W_hh  = (const float*)d_in[3];
    const float* b_ih  = (const float*)d_in[4];
    const float* b_hh  = (const float*)d_in[5];
    const float* W_fc  = (const float*)d_in[6];
    const float* b_fc  = (const float*)d_in[7];
    float* out = (float*)d_out;

    lstm_wpl_k<<<dim3(B_ / 8), dim3(256), 0, stream>>>(
        x, W_ih0, W_ihr, W_hh, b_ih, b_hh, W_fc, b_fc, out);
}

// Round 4
// 540.113 us; speedup vs baseline: 1.7872x; 1.7872x over previous
//
#include <hip/hip_runtime.h>

// Stacked LSTM B=2048,T=512,IN=4,H=64,L=4,OUT=5 — R10 flag-ring CHAMPION +
// R13 learnings. Scoreboard: R10 ring 603us / R11 skew 639 / R12 half-phase
// 713 / R13 wave-per-layer 965 (no TLP: 1 wave/SIMD exposes all latency, but
// PROVED identity-k + XOR swizzle kills bank conflicts 4.8e7 -> 4.6e5).
// Floor: 60-64 MFMA/SIMD/step x 19.4 cyc = ~1180 cyc = 255us; useful
// VALU+trans ~830 cyc fits underneath with 4 waves/SIMD.
// This kernel = R10's EXACT 16-wave depth-4 ring + flag protocol, changing:
//  1. identity-k LDS layout, rows 128 B, XOR swizzle byte^=((r&7)<<4) on
//     both write and read (T2 both-sides) -> conflicts ~0.
//  2. wI duplicate write DELETED: layer l's input(t) == layer l-1's own-h
//     slot (t+1)&3 (identity layout makes regions congruent). Race-free:
//     prev>=t+1 guards data; prev overwrites that slot only at its step
//     t+4 gated by its next>=t+1 (we release t+1 only after consuming).
//  3. GEMM split: input-half MFMAs (kt2/3, NOT on the recurrence) issue
//     right after the prev poll; recurrence chain is then only
//     partner-poll -> own-h read -> 2-deep MFMA -> pointwise -> write.
//  4. s_setprio(1) around the critical h-MFMA+pointwise section (T5:
//     drifted waves = role diversity, the regime where setprio pays).
// Flag deps (wave (l,jj) before step t): partners >= t (h(t-1) ready),
// prev >= t+1 (input h_{l-1}(t) ready), next >= t-3 (WAR on own slot
// (t+1)&3). Own-slot WAR vs partners covered by partners>=t (R10 proof).
// Math identical to validated R10 (absmax 4.9e-4): f16 weights+acts,
// prescale -log2e (i,f,o) / +2log2e (g) -> direct exp2; zero-C MFMA via
// input-half, bias in pointwise; rho(b)=4*(b>>1)+(b&1) row spread.
// A-frag: row=lane&15 (batch), k=(lane>>4)*8+e (unit, IDENTITY). C: col=
// lane&15 (unit), row=(lane>>4)*4+reg (batch rows 4q+rr, rr<2 real).

#define B_    2048
#define T_    512
#define H_    64
#define OUT_  5
#define LOG2E 1.44269504088896340736f

typedef _Float16 f16;
typedef __attribute__((ext_vector_type(4))) _Float16 f16x4;
typedef __attribute__((ext_vector_type(8))) _Float16 f16x8;
typedef __attribute__((ext_vector_type(4))) float f32x4;
typedef __attribute__((ext_vector_type(2))) unsigned long long u64x2;

__device__ __forceinline__ float rcpf(float v) { return __builtin_amdgcn_rcpf(v); }
__device__ __forceinline__ float ex2(float v)  { return __builtin_amdgcn_exp2f(v); }

__global__ __launch_bounds__(1024, 4) void lstm_ring2_k(
    const float* __restrict__ x,      // [B,T,4]
    const float* __restrict__ W_ih0,  // [256,4]
    const float* __restrict__ W_ihr,  // [3,256,64]
    const float* __restrict__ W_hh,   // [4,256,64]
    const float* __restrict__ b_ih,   // [4,256]
    const float* __restrict__ b_hh,   // [4,256]
    const float* __restrict__ W_fc,   // [5,64]
    const float* __restrict__ b_fc,   // [5]
    float* __restrict__ out)          // [B,5]
{
    const int tid  = threadIdx.x;
    const int wave = tid >> 6;        // 0..15
    const int l    = wave >> 2;       // layer 0..3
    const int jj   = wave & 3;        // quarter of the layer's units
    const int lane = tid & 63;
    const int q    = lane >> 4;
    const int ln   = lane & 15;
    const int b0   = blockIdx.x * 8;

    // [layer][slot 0..3][16 rows x 64 f16], row=128 B, XOR-swizzled. 32 KB.
    __shared__ f16  hbuf[4][4][1024];
    __shared__ f16  xlds[T_][8][4];    // 32 KB
    __shared__ float hf[8][H_ + 1];    // FC staging
    __shared__ int  flg[16];

    for (int k = tid; k < 8192; k += 1024) ((unsigned*)hbuf)[k] = 0u;
    if (tid < 16) flg[tid] = 0;

    // ---- one-time x preload -> xlds (f16), coalesced float4 reads ----
#pragma unroll
    for (int k = 0; k < 4; ++k) {
        const int idx = tid + k * 1024;              // 0..4095
        const int bb  = idx >> 9, tt = idx & 511;
        const float4 v = *(const float4*)(x + (size_t)(b0 + bb) * (T_ * 4) + tt * 4);
        f16x4 h4; h4[0] = (f16)v.x; h4[1] = (f16)v.y; h4[2] = (f16)v.z; h4[3] = (f16)v.w;
        *(f16x4*)&xlds[tt][bb][0] = h4;
    }

    // ---- weights -> f16 B-frags (4 gates x 4 kt = 64 VGPR), prescaled ----
    // B-frag: col=lane&15 -> unit n; k = kt*32 + q*8 + e (identity).
    const float* Whh = W_hh + (size_t)l * 256 * 64;
    const float* Wih = (l == 0) ? W_ih0 : (W_ihr + (size_t)(l - 1) * 256 * 64);
    const float scg[4] = {-LOG2E, -LOG2E, 2.0f * LOG2E, -LOG2E};

    f16x8 Wf[4][4];                   // [gate][kt]; kt0/1 = h, kt2/3 = input
    float biasv[4];
#pragma unroll
    for (int g4 = 0; g4 < 4; ++g4) {
        const int n = g4 * 64 + jj * 16 + ln;
        biasv[g4] = (b_ih[l * 256 + n] + b_hh[l * 256 + n]) * scg[g4];
#pragma unroll
        for (int kt = 0; kt < 4; ++kt) {
            f16x8 f;
#pragma unroll
            for (int e = 0; e < 8; ++e) {
                float wv;
                if (kt < 2)      wv = Whh[n * 64 + kt * 32 + q * 8 + e];
                else if (l == 0) wv = (kt == 2 && q == 0 && e < 4) ? Wih[n * 4 + e] : 0.0f;
                else             wv = Wih[n * 64 + (kt - 2) * 32 + q * 8 + e];
                f[e] = (f16)(wv * scg[g4]);
            }
            Wf[g4][kt] = f;
        }
    }

    // ---- per-lane LDS byte offsets (swizzled) ----
    const int swz   = (ln & 7) << 4;
    const int roffA = (ln * 128 + q * 16) ^ swz;        // k-octets 0..3
    const int roffB = (ln * 128 + 64 + q * 16) ^ swz;   // k-octets 4..7
    char* ownB      = (char*)&hbuf[l][0][0];
    const char* prvB = (const char*)&hbuf[(l > 0) ? (l - 1) : 0][0][0];

    int woff[2];
#pragma unroll
    for (int rr = 0; rr < 2; ++rr) {
        const int r = 4 * q + rr;
        woff[rr] = (r * 128 + (jj * 16 + ln) * 2) ^ ((r & 7) << 4);
    }
    const int  xb  = 2 * (ln >> 2) + (ln & 1);      // batch for x-frag row ln
    const bool xok = (q == 0) && ((ln & 3) < 2);    // real batch rows only

    // ---- flag-watch lane assignments ----
    // poll1 (input ready): lanes 0..3 watch prev-layer waves, >= t+1
    const bool fU1 = (l > 0) && (lane < 4);
    const int  fI1 = fU1 ? (4 * (l - 1) + lane) : 0;
    // poll2: lanes 0..2 partners >= t; lanes 3..6 next >= t-3
    int fI2 = 0, fO2 = 0; bool fU2 = false;
    if (lane < 3)                { fI2 = 4 * l + ((jj + 1 + lane) & 3); fO2 = 0;  fU2 = true; }
    else if (lane < 7 && l < 3)  { fI2 = 4 * (l + 1) + (lane - 3);      fO2 = -3; fU2 = true; }

    __syncthreads();                  // zero-init + xlds + flg visible

    const f32x4 Z0 = {0.f, 0.f, 0.f, 0.f};
    float cst[2] = {0.f, 0.f};        // c-state (batches 2q+rr)

    auto body = [&](const int t, const int sl, const int sn) {
        // ---- phase 1: input half (off the recurrence) ----
        f32x4 acc[4];
        if (l > 0) {
            unsigned g = 0;                          // poll prev >= t+1
            for (;;) {
                int v = 0x7fffffff;
                if (fU1) v = __hip_atomic_load(&flg[fI1], __ATOMIC_ACQUIRE,
                                               __HIP_MEMORY_SCOPE_WORKGROUP);
                if (__all(v >= t + 1)) break;
                if (++g > 2) __builtin_amdgcn_s_sleep(1);
                if (g > (1u << 16)) break;
            }
            const char* ri = prvB + sn * 2048;       // h_{l-1}(t)
            const f16x8 A2 = *(const f16x8*)(ri + roffA);
            const f16x8 A3 = *(const f16x8*)(ri + roffB);
#pragma unroll
            for (int g4 = 0; g4 < 4; ++g4)
                acc[g4] = __builtin_amdgcn_mfma_f32_16x16x32_f16(A2, Wf[g4][2], Z0, 0, 0, 0);
#pragma unroll
            for (int g4 = 0; g4 < 4; ++g4)
                acc[g4] = __builtin_amdgcn_mfma_f32_16x16x32_f16(A3, Wf[g4][3], acc[g4], 0, 0, 0);
        } else {
            unsigned long long xw = 0ull;
            if (xok) xw = *(const unsigned long long*)&xlds[t][xb][0];
            u64x2 tmp; tmp[0] = xw; tmp[1] = 0ull;
            const f16x8 A2 = __builtin_bit_cast(f16x8, tmp);  // x(t) @ k=64..67
#pragma unroll
            for (int g4 = 0; g4 < 4; ++g4)
                acc[g4] = __builtin_amdgcn_mfma_f32_16x16x32_f16(A2, Wf[g4][2], Z0, 0, 0, 0);
            // kt3 identically 0 for l==0: skipped (exact)
        }

        // ---- phase 2: recurrence-critical half ----
        {
            unsigned g = 0;                          // partners >= t, next >= t-3
            for (;;) {
                int v = 0x7fffffff;
                if (fU2) v = __hip_atomic_load(&flg[fI2], __ATOMIC_ACQUIRE,
                                               __HIP_MEMORY_SCOPE_WORKGROUP);
                if (__all(v >= t + fO2)) break;
                if (++g > 2) __builtin_amdgcn_s_sleep(1);
                if (g > (1u << 16)) break;
            }
        }
        const char* ro = ownB + sl * 2048;           // h_l(t-1)
        const f16x8 A0 = *(const f16x8*)(ro + roffA);
        const f16x8 A1 = *(const f16x8*)(ro + roffB);
        __builtin_amdgcn_s_setprio(1);
#pragma unroll
        for (int g4 = 0; g4 < 4; ++g4)
            acc[g4] = __builtin_amdgcn_mfma_f32_16x16x32_f16(A0, Wf[g4][0], acc[g4], 0, 0, 0);
#pragma unroll
        for (int g4 = 0; g4 < 4; ++g4)
            acc[g4] = __builtin_amdgcn_mfma_f32_16x16x32_f16(A1, Wf[g4][1], acc[g4], 0, 0, 0);

        char* wr = ownB + sn * 2048;                 // h(t) -> slot (t+1)&3
#pragma unroll
        for (int rr = 0; rr < 2; ++rr) {
            const float si = rcpf(1.0f + ex2(acc[0][rr] + biasv[0]));
            const float sf = rcpf(1.0f + ex2(acc[1][rr] + biasv[1]));
            const float tg = 1.0f - 2.0f * rcpf(1.0f + ex2(acc[2][rr] + biasv[2]));
            const float so = rcpf(1.0f + ex2(acc[3][rr] + biasv[3]));
            const float c  = sf * cst[rr] + si * tg;
            cst[rr] = c;
            const float tc = 1.0f - 2.0f * rcpf(1.0f + ex2(c * (2.0f * LOG2E)));
            const float h  = so * tc;
            *(f16*)(wr + woff[rr]) = (f16)h;
            if (l == 3 && t == T_ - 1) hf[2 * q + rr][jj * 16 + ln] = h;
        }
        __builtin_amdgcn_s_setprio(0);

        if (lane == 0)                // release: drains LDS writes first
            __hip_atomic_store(&flg[wave], t + 1, __ATOMIC_RELEASE,
                               __HIP_MEMORY_SCOPE_WORKGROUP);
    };

#pragma unroll 1
    for (int t = 0; t < T_; t += 4) {                // slots folded to constants
        body(t,     0, 1);
        body(t + 1, 1, 2);
        body(t + 2, 2, 3);
        body(t + 3, 3, 0);
    }

    // ---- FC on h(T-1) of layer 3 ----
    __syncthreads();
    if (tid < 8 * OUT_) {
        const int b = tid / OUT_, o = tid % OUT_;
        float a = b_fc[o];
#pragma unroll
        for (int k = 0; k < H_; ++k)
            a = fmaf(hf[b][k], W_fc[o * H_ + k], a);
        out[(b0 + b) * OUT_ + o] = a;
    }
}

extern "C" void kernel_launch(void* const* d_in, const int* in_sizes, int n_in,
                              void* d_out, int out_size, void* d_ws, size_t ws_size,
                              hipStream_t stream) {
    const float* x     = (const float*)d_in[0];
    const float* W_ih0 = (const float*)d_in[1];
    const float* W_ihr = (const float*)d_in[2];
    const float* W_hh  = (const float*)d_in[3];
    const float* b_ih  = (const float*)d_in[4];
    const float* b_hh  = (const float*)d_in[5];
    const float* W_fc  = (const float*)d_in[6];
    const float* b_fc  = (const float*)d_in[7];
    float* out = (float*)d_out;

    lstm_ring2_k<<<dim3(B_ / 8), dim3(1024), 0, stream>>>(
        x, W_ih0, W_ihr, W_hh, b_ih, b_hh, W_fc, b_fc, out);
}

// Round 5
// 509.230 us; speedup vs baseline: 1.8956x; 1.0606x over previous
//
#include <hip/hip_runtime.h>

// Stacked LSTM B=2048,T=512,IN=4,H=64,L=4,OUT=5 — R14 champion (540us) +
// trans-pipe reduction. Scoreboard: R10 ring 603 / R11 skew 639 / R12
// half-phase 713 / R13 wave-per-layer 965 / R14 ring2 540us (MfmaUtil 41%,
// VALUBusy 69%, conflicts 4.6e5).
// R14 wall = 2530 cyc/SIMD/step: MFMA 1040, VALU-issue 1745 (of which trans
// ~1280: 20 trans/lane/step at ~16cyc/wave64 — the BINDING pipe), ~785
// neither-pipe (handoff+latency exposure). This round shrinks the trans
// stream, leaving the proven ring protocol untouched:
//  1. fused gate products: si*tanh(g) = (Eg-1)*rcp((1+Ei)(1+Eg)),
//     so*tanh(c) = (Ec-1)*rcp((1+Eo)(1+Ec)) -> 8 trans/update (was 10).
//  2. bias folded into MFMA C-operand (Cb broadcast) -> -8 VALU adds/lane.
//  3. cell state carried SCALED: C' = 2log2e*c -> removes the mul from the
//     c->exp2 dependent chain (C' = sf*C'_prev + 2log2e*si*tg, exact fold).
// Ring protocol (unchanged, R14-proven): 16 waves, depth-4 slot ring,
// identity-k layout rows 128 B XOR-swizzled ((r&7)<<4, both sides); input(t)
// of layer l read directly from layer l-1's own-h slot (t+1)&3; GEMM split:
// input-half MFMAs (kt2/3) after prev-poll, recurrence half (kt0/1) after
// partner-poll; setprio(1) around critical section.
// Flag deps (wave (l,jj) before step t): partners >= t, prev >= t+1,
// next >= t-3 (WAR). A-frag: row=lane&15 (batch), k=(lane>>4)*8+e (unit,
// identity). C: col=lane&15 (unit), row=(lane>>4)*4+reg (rows 4q+rr, rr<2
// real, batch b=2q+rr).

#define B_    2048
#define T_    512
#define H_    64
#define OUT_  5
#define LOG2E 1.44269504088896340736f

typedef _Float16 f16;
typedef __attribute__((ext_vector_type(4))) _Float16 f16x4;
typedef __attribute__((ext_vector_type(8))) _Float16 f16x8;
typedef __attribute__((ext_vector_type(4))) float f32x4;
typedef __attribute__((ext_vector_type(2))) unsigned long long u64x2;

__device__ __forceinline__ float rcpf(float v) { return __builtin_amdgcn_rcpf(v); }
__device__ __forceinline__ float ex2(float v)  { return __builtin_amdgcn_exp2f(v); }

__global__ __launch_bounds__(1024, 4) void lstm_ring3_k(
    const float* __restrict__ x,      // [B,T,4]
    const float* __restrict__ W_ih0,  // [256,4]
    const float* __restrict__ W_ihr,  // [3,256,64]
    const float* __restrict__ W_hh,   // [4,256,64]
    const float* __restrict__ b_ih,   // [4,256]
    const float* __restrict__ b_hh,   // [4,256]
    const float* __restrict__ W_fc,   // [5,64]
    const float* __restrict__ b_fc,   // [5]
    float* __restrict__ out)          // [B,5]
{
    const int tid  = threadIdx.x;
    const int wave = tid >> 6;        // 0..15
    const int l    = wave >> 2;       // layer 0..3
    const int jj   = wave & 3;        // quarter of the layer's units
    const int lane = tid & 63;
    const int q    = lane >> 4;
    const int ln   = lane & 15;
    const int b0   = blockIdx.x * 8;

    // [layer][slot 0..3][16 rows x 64 f16], row=128 B, XOR-swizzled. 32 KB.
    __shared__ f16  hbuf[4][4][1024];
    __shared__ f16  xlds[T_][8][4];    // 32 KB
    __shared__ float hf[8][H_ + 1];    // FC staging
    __shared__ int  flg[16];

    for (int k = tid; k < 8192; k += 1024) ((unsigned*)hbuf)[k] = 0u;
    if (tid < 16) flg[tid] = 0;

    // ---- one-time x preload -> xlds (f16), coalesced float4 reads ----
#pragma unroll
    for (int k = 0; k < 4; ++k) {
        const int idx = tid + k * 1024;              // 0..4095
        const int bb  = idx >> 9, tt = idx & 511;
        const float4 v = *(const float4*)(x + (size_t)(b0 + bb) * (T_ * 4) + tt * 4);
        f16x4 h4; h4[0] = (f16)v.x; h4[1] = (f16)v.y; h4[2] = (f16)v.z; h4[3] = (f16)v.w;
        *(f16x4*)&xlds[tt][bb][0] = h4;
    }

    // ---- weights -> f16 B-frags (4 gates x 4 kt = 64 VGPR), prescaled ----
    const float* Whh = W_hh + (size_t)l * 256 * 64;
    const float* Wih = (l == 0) ? W_ih0 : (W_ihr + (size_t)(l - 1) * 256 * 64);
    const float scg[4] = {-LOG2E, -LOG2E, 2.0f * LOG2E, -LOG2E};

    f16x8 Wf[4][4];                   // [gate][kt]; kt0/1 = h, kt2/3 = input
    f32x4 Cb[4];                      // bias as MFMA C-init (broadcast rows)
#pragma unroll
    for (int g4 = 0; g4 < 4; ++g4) {
        const int n = g4 * 64 + jj * 16 + ln;
        const float bv = (b_ih[l * 256 + n] + b_hh[l * 256 + n]) * scg[g4];
        Cb[g4][0] = bv; Cb[g4][1] = bv; Cb[g4][2] = bv; Cb[g4][3] = bv;
#pragma unroll
        for (int kt = 0; kt < 4; ++kt) {
            f16x8 f;
#pragma unroll
            for (int e = 0; e < 8; ++e) {
                float wv;
                if (kt < 2)      wv = Whh[n * 64 + kt * 32 + q * 8 + e];
                else if (l == 0) wv = (kt == 2 && q == 0 && e < 4) ? Wih[n * 4 + e] : 0.0f;
                else             wv = Wih[n * 64 + (kt - 2) * 32 + q * 8 + e];
                f[e] = (f16)(wv * scg[g4]);
            }
            Wf[g4][kt] = f;
        }
    }

    // ---- per-lane LDS byte offsets (swizzled) ----
    const int swz   = (ln & 7) << 4;
    const int roffA = (ln * 128 + q * 16) ^ swz;        // k-octets 0..3
    const int roffB = (ln * 128 + 64 + q * 16) ^ swz;   // k-octets 4..7
    char* ownB      = (char*)&hbuf[l][0][0];
    const char* prvB = (const char*)&hbuf[(l > 0) ? (l - 1) : 0][0][0];

    int woff[2];
#pragma unroll
    for (int rr = 0; rr < 2; ++rr) {
        const int r = 4 * q + rr;
        woff[rr] = (r * 128 + (jj * 16 + ln) * 2) ^ ((r & 7) << 4);
    }
    const int  xb  = 2 * (ln >> 2) + (ln & 1);      // batch for x-frag row ln
    const bool xok = (q == 0) && ((ln & 3) < 2);    // real batch rows only

    // ---- flag-watch lane assignments ----
    const bool fU1 = (l > 0) && (lane < 4);
    const int  fI1 = fU1 ? (4 * (l - 1) + lane) : 0;
    int fI2 = 0, fO2 = 0; bool fU2 = false;
    if (lane < 3)                { fI2 = 4 * l + ((jj + 1 + lane) & 3); fO2 = 0;  fU2 = true; }
    else if (lane < 7 && l < 3)  { fI2 = 4 * (l + 1) + (lane - 3);      fO2 = -3; fU2 = true; }

    __syncthreads();                  // zero-init + xlds + flg visible

    float cst[2] = {0.f, 0.f};        // SCALED cell state C' = 2log2e * c
    const float K2 = 2.0f * LOG2E;

    auto body = [&](const int t, const int sl, const int sn) {
        // ---- phase 1: input half (off the recurrence), C = bias ----
        f32x4 acc[4];
        if (l > 0) {
            unsigned g = 0;                          // poll prev >= t+1
            for (;;) {
                int v = 0x7fffffff;
                if (fU1) v = __hip_atomic_load(&flg[fI1], __ATOMIC_ACQUIRE,
                                               __HIP_MEMORY_SCOPE_WORKGROUP);
                if (__all(v >= t + 1)) break;
                if (++g > 2) __builtin_amdgcn_s_sleep(1);
                if (g > (1u << 16)) break;
            }
            const char* ri = prvB + sn * 2048;       // h_{l-1}(t)
            const f16x8 A2 = *(const f16x8*)(ri + roffA);
            const f16x8 A3 = *(const f16x8*)(ri + roffB);
#pragma unroll
            for (int g4 = 0; g4 < 4; ++g4)
                acc[g4] = __builtin_amdgcn_mfma_f32_16x16x32_f16(A2, Wf[g4][2], Cb[g4], 0, 0, 0);
#pragma unroll
            for (int g4 = 0; g4 < 4; ++g4)
                acc[g4] = __builtin_amdgcn_mfma_f32_16x16x32_f16(A3, Wf[g4][3], acc[g4], 0, 0, 0);
        } else {
            unsigned long long xw = 0ull;
            if (xok) xw = *(const unsigned long long*)&xlds[t][xb][0];
            u64x2 tmp; tmp[0] = xw; tmp[1] = 0ull;
            const f16x8 A2 = __builtin_bit_cast(f16x8, tmp);  // x(t) @ k=64..67
#pragma unroll
            for (int g4 = 0; g4 < 4; ++g4)
                acc[g4] = __builtin_amdgcn_mfma_f32_16x16x32_f16(A2, Wf[g4][2], Cb[g4], 0, 0, 0);
            // kt3 identically 0 for l==0: skipped (exact)
        }

        // ---- phase 2: recurrence-critical half ----
        {
            unsigned g = 0;                          // partners >= t, next >= t-3
            for (;;) {
                int v = 0x7fffffff;
                if (fU2) v = __hip_atomic_load(&flg[fI2], __ATOMIC_ACQUIRE,
                                               __HIP_MEMORY_SCOPE_WORKGROUP);
                if (__all(v >= t + fO2)) break;
                if (++g > 2) __builtin_amdgcn_s_sleep(1);
                if (g > (1u << 16)) break;
            }
        }
        const char* ro = ownB + sl * 2048;           // h_l(t-1)
        const f16x8 A0 = *(const f16x8*)(ro + roffA);
        const f16x8 A1 = *(const f16x8*)(ro + roffB);
        __builtin_amdgcn_s_setprio(1);
#pragma unroll
        for (int g4 = 0; g4 < 4; ++g4)
            acc[g4] = __builtin_amdgcn_mfma_f32_16x16x32_f16(A0, Wf[g4][0], acc[g4], 0, 0, 0);
#pragma unroll
        for (int g4 = 0; g4 < 4; ++g4)
            acc[g4] = __builtin_amdgcn_mfma_f32_16x16x32_f16(A1, Wf[g4][1], acc[g4], 0, 0, 0);

        // ---- pointwise: 8 trans/update (fused), scaled cell state ----
        char* wr = ownB + sn * 2048;                 // h(t) -> slot (t+1)&3
#pragma unroll
        for (int rr = 0; rr < 2; ++rr) {
            const float Ei = ex2(acc[0][rr]);        // e^{-i}
            const float Ef = ex2(acc[1][rr]);        // e^{-f}
            const float Eg = ex2(acc[2][rr]);        // e^{+2g}
            const float Eo = ex2(acc[3][rr]);        // e^{-o}
            const float sf   = rcpf(1.0f + Ef);                  // sigmoid(f)
            const float di   = (1.0f + Ei) * (1.0f + Eg);
            const float sitg = fmaf(Eg, K2, -K2) * rcpf(di);     // 2log2e*si*tg
            const float Cp   = fmaf(sf, cst[rr], sitg);          // C'=2log2e*c
            cst[rr] = Cp;
            const float Ec = ex2(Cp);                // e^{+2c}
            const float dc = (1.0f + Eo) * (1.0f + Ec);
            const float h  = (Ec - 1.0f) * rcpf(dc); // sigmoid(o)*tanh(c)
            *(f16*)(wr + woff[rr]) = (f16)h;
            if (l == 3 && t == T_ - 1) hf[2 * q + rr][jj * 16 + ln] = h;
        }
        __builtin_amdgcn_s_setprio(0);

        if (lane == 0)                // release: drains LDS writes first
            __hip_atomic_store(&flg[wave], t + 1, __ATOMIC_RELEASE,
                               __HIP_MEMORY_SCOPE_WORKGROUP);
    };

#pragma unroll 1
    for (int t = 0; t < T_; t += 4) {                // slots folded to constants
        body(t,     0, 1);
        body(t + 1, 1, 2);
        body(t + 2, 2, 3);
        body(t + 3, 3, 0);
    }

    // ---- FC on h(T-1) of layer 3 ----
    __syncthreads();
    if (tid < 8 * OUT_) {
        const int b = tid / OUT_, o = tid % OUT_;
        float a = b_fc[o];
#pragma unroll
        for (int k = 0; k < H_; ++k)
            a = fmaf(hf[b][k], W_fc[o * H_ + k], a);
        out[(b0 + b) * OUT_ + o] = a;
    }
}

extern "C" void kernel_launch(void* const* d_in, const int* in_sizes, int n_in,
                              void* d_out, int out_size, void* d_ws, size_t ws_size,
                              hipStream_t stream) {
    const float* x     = (const float*)d_in[0];
    const float* W_ih0 = (const float*)d_in[1];
    const float* W_ihr = (const float*)d_in[2];
    const float* W_hh  = (const float*)d_in[3];
    const float* b_ih  = (const float*)d_in[4];
    const float* b_hh  = (const float*)d_in[5];
    const float* W_fc  = (const float*)d_in[6];
    const float* b_fc  = (const float*)d_in[7];
    float* out = (float*)d_out;

    lstm_ring3_k<<<dim3(B_ / 8), dim3(1024), 0, stream>>>(
        x, W_ih0, W_ihr, W_hh, b_ih, b_hh, W_fc, b_fc, out);
}